// Round 6
// baseline (192.915 us; speedup 1.0000x reference)
//
#include <hip/hip_runtime.h>
#include <math.h>

#define BB 2
#define SS 192
#define DD 512
#define HH 8
#define HD 64
#define QCB 4                 // q-rows per block
#define NQC (SS / QCB)        // 48 q-chunks
#define PROJ_N (BB*HH*SS*HD)
#define SCL (0.125f * 1.44269504088896f)   // 1/sqrt(64) * log2(e)

typedef __attribute__((ext_vector_type(8))) short bf16x8;
typedef __attribute__((ext_vector_type(4))) float f32x4;
typedef __attribute__((ext_vector_type(4))) unsigned uint4v;
typedef _Float16 f16x8 __attribute__((ext_vector_type(8)));

__device__ __forceinline__ unsigned cvt_pk_bf16(float a, float b) {
    unsigned r;
    asm("v_cvt_pk_bf16_f32 %0, %1, %2" : "=v"(r) : "v"(a), "v"(b));
    return r;
}
// x[0..7] ~= hi + lo (split-bf16, rel err ~2^-17) -- used by projection GEMMs
__device__ __forceinline__ void split8_pk(const float* x, uint4v& hi, uint4v& lo) {
#pragma unroll
    for (int p = 0; p < 4; ++p) {
        const float a = x[2 * p], b = x[2 * p + 1];
        const unsigned h = cvt_pk_bf16(a, b);
        const float ra = a - __uint_as_float(h << 16);
        const float rb = b - __uint_as_float(h & 0xFFFF0000u);
        hi[p] = h;
        lo[p] = cvt_pk_bf16(ra, rb);
    }
}

// pack 8 f32 -> f16x8 via v_cvt_pkrtz_f16_f32 (hot path)
__device__ __forceinline__ f16x8 pack8_f16(const float* g) {
    uint4v u;
#pragma unroll
    for (int p = 0; p < 4; ++p)
        u[p] = __builtin_bit_cast(unsigned,
                                  __builtin_amdgcn_cvt_pkrtz(g[2 * p], g[2 * p + 1]));
    return __builtin_bit_cast(f16x8, u);
}

// ---------------------------------------------------------------------------
// Split-bf16 MFMA GEMM: y = x @ W^T   (x: M x 512, W: 512 x 512, f32)
// 64x64 tile / block, 256 thr (4 waves, 2x2), BK=32, double-buffered LDS.
// ---------------------------------------------------------------------------
template <int SPLIT>
__device__ __forceinline__ void gemm_mfma_body(const float* __restrict__ x,
                                               const float* __restrict__ W,
                                               float* __restrict__ y) {
    __shared__ short Ahs[2][4 * 64 * 8], Als[2][4 * 64 * 8];
    __shared__ short Bhs[2][4 * 64 * 8], Bls[2][4 * 64 * 8];

    const int t = threadIdx.x;
    const int lane = t & 63, w = t >> 6;
    const int wr = w >> 1, wc = w & 1;
    const int c16 = lane & 15, q4 = lane >> 4;
    const int m0 = blockIdx.x * 64, n0 = blockIdx.y * 64;
    const int sr = t >> 2, scc = t & 3;

    f32x4 acc[2][2];
#pragma unroll
    for (int a = 0; a < 2; ++a)
#pragma unroll
        for (int b = 0; b < 2; ++b) acc[a][b] = (f32x4){0.f, 0.f, 0.f, 0.f};

#define STAGE(kk, bf)                                                              \
    {                                                                              \
        float a8[8], w8[8];                                                        \
        *(f32x4*)&a8[0] = *(const f32x4*)&x[(m0 + sr) * 512 + (kk) + scc * 8];     \
        *(f32x4*)&a8[4] = *(const f32x4*)&x[(m0 + sr) * 512 + (kk) + scc * 8 + 4]; \
        *(f32x4*)&w8[0] = *(const f32x4*)&W[(n0 + sr) * 512 + (kk) + scc * 8];     \
        *(f32x4*)&w8[4] = *(const f32x4*)&W[(n0 + sr) * 512 + (kk) + scc * 8 + 4]; \
        uint4v h, l;                                                               \
        split8_pk(a8, h, l);                                                       \
        *(uint4v*)&Ahs[bf][(scc * 64 + sr) * 8] = h;                               \
        *(uint4v*)&Als[bf][(scc * 64 + sr) * 8] = l;                               \
        split8_pk(w8, h, l);                                                       \
        *(uint4v*)&Bhs[bf][(scc * 64 + sr) * 8] = h;                               \
        *(uint4v*)&Bls[bf][(scc * 64 + sr) * 8] = l;                               \
    }

    STAGE(0, 0)
    for (int s = 0; s < 16; ++s) {
        __syncthreads();
        if (s + 1 < 16) STAGE((s + 1) * 32, (s + 1) & 1)
        const int b = s & 1;
        bf16x8 aH[2], aL[2], bH[2], bL[2];
#pragma unroll
        for (int mt = 0; mt < 2; ++mt) {
            const int row = wr * 32 + mt * 16 + c16;
            aH[mt] = *(const bf16x8*)&Ahs[b][(q4 * 64 + row) * 8];
            aL[mt] = *(const bf16x8*)&Als[b][(q4 * 64 + row) * 8];
        }
#pragma unroll
        for (int nt = 0; nt < 2; ++nt) {
            const int col = wc * 32 + nt * 16 + c16;
            bH[nt] = *(const bf16x8*)&Bhs[b][(q4 * 64 + col) * 8];
            bL[nt] = *(const bf16x8*)&Bls[b][(q4 * 64 + col) * 8];
        }
#pragma unroll
        for (int mt = 0; mt < 2; ++mt)
#pragma unroll
            for (int nt = 0; nt < 2; ++nt) {
                acc[mt][nt] = __builtin_amdgcn_mfma_f32_16x16x32_bf16(aH[mt], bH[nt], acc[mt][nt], 0, 0, 0);
                acc[mt][nt] = __builtin_amdgcn_mfma_f32_16x16x32_bf16(aH[mt], bL[nt], acc[mt][nt], 0, 0, 0);
                acc[mt][nt] = __builtin_amdgcn_mfma_f32_16x16x32_bf16(aL[mt], bH[nt], acc[mt][nt], 0, 0, 0);
            }
    }
#undef STAGE

#pragma unroll
    for (int mt = 0; mt < 2; ++mt)
#pragma unroll
        for (int nt = 0; nt < 2; ++nt)
#pragma unroll
            for (int j = 0; j < 4; ++j) {
                const int n_row = m0 + wr * 32 + mt * 16 + q4 * 4 + j;
                const int col = n0 + wc * 32 + nt * 16 + c16;
                const float v = acc[mt][nt][j];
                if (SPLIT) {
                    const int b = n_row / SS, s2 = n_row % SS;
                    const int h = col >> 6, e = col & 63;
                    y[((b * HH + h) * SS + s2) * HD + e] = v;
                } else {
                    y[n_row * 512 + col] = v;
                }
            }
}

__global__ __launch_bounds__(256) void proj4_kernel(
    const float* __restrict__ xq, const float* __restrict__ xk,
    const float* __restrict__ xl, const float* __restrict__ xv,
    const float* __restrict__ Wq, const float* __restrict__ Wk,
    const float* __restrict__ Wv, float* __restrict__ ws) {
    const int p = blockIdx.z;
    const float* x = (p == 0) ? xq : (p == 1) ? xk : (p == 2) ? xl : xv;
    const float* W = (p == 0) ? Wq : (p == 3) ? Wv : Wk;
    gemm_mfma_body<1>(x, W, ws + p * PROJ_N);
}

__global__ __launch_bounds__(256) void outproj_kernel(
    const float* __restrict__ att, const float* __restrict__ Wout,
    float* __restrict__ out) {
    gemm_mfma_body<0>(att, Wout, out);
}

// ---------------------------------------------------------------------------
// Barrier-free MFMA rank-3 attention, 3 blocks/CU.
// Grid 768 = 16 bh x 48 qc (QCB=4). 512 thr = 8 waves (2 lg x 4 kg).
// A = L rows (f16, regs, q-invariant). B = G = K*q built per-lane in regs.
// No barriers in the q loop; raw v_exp_f32; stats via one end barrier.
// ---------------------------------------------------------------------------
__global__ __launch_bounds__(512, 6) void attn3d_mfma_kernel(
    const float* __restrict__ qh, const float* __restrict__ kh,
    const float* __restrict__ lh, const float* __restrict__ vh,
    float* __restrict__ att) {
    __shared__ float qs[QCB][64];          // 1 KB
    __shared__ float partial[2][QCB][192]; // 6 KB
    __shared__ float Wt[QCB][192];         // 3 KB
    __shared__ float epart[QCB][64];       // 1 KB
    __shared__ float zinv[QCB];

    const int blk = blockIdx.x;
    const int bh = blk / NQC, qc = blk - bh * NQC;
    const int t = threadIdx.x;
    const int lane = t & 63, w = t >> 6;
    const int lg = w >> 2, kg = w & 3;
    const int c = lane & 15, eh = lane >> 4;

    // stage q rows (scale+log2e folded)
    if (t < QCB * 64) {
        const int q = t >> 6, e = t & 63;
        qs[q][e] = qh[(bh * SS + qc * QCB + q) * HD + e] * SCL;
    }

    // K slice in registers: col = kg*48+kt*16+c, e = s*32+eh*8..
    float Kreg[3][2][8];
#pragma unroll
    for (int kt = 0; kt < 3; ++kt)
#pragma unroll
        for (int s = 0; s < 2; ++s) {
            const int col = kg * 48 + kt * 16 + c;
            const float* kp = &kh[(bh * SS + col) * HD + s * 32 + eh * 8];
            *(f32x4*)&Kreg[kt][s][0] = *(const f32x4*)&kp[0];
            *(f32x4*)&Kreg[kt][s][4] = *(const f32x4*)&kp[4];
        }

    // A fragments: L rows as single f16 (RTZ pack), q-invariant
    f16x8 Af[6][2];
#pragma unroll
    for (int lt = 0; lt < 6; ++lt)
#pragma unroll
        for (int s = 0; s < 2; ++s) {
            const int row = lg * 96 + lt * 16 + c;
            float buf8[8];
            const float* lp = &lh[(bh * SS + row) * HD + s * 32 + eh * 8];
            *(f32x4*)&buf8[0] = *(const f32x4*)&lp[0];
            *(f32x4*)&buf8[4] = *(const f32x4*)&lp[4];
            Af[lt][s] = pack8_f16(buf8);
        }
    __syncthreads();   // qs ready

    // ---- barrier-free q loop ----
    for (int q = 0; q < QCB; ++q) {
        float qv[2][8];
#pragma unroll
        for (int s = 0; s < 2; ++s) {
            *(f32x4*)&qv[s][0] = *(const f32x4*)&qs[q][s * 32 + eh * 8];
            *(f32x4*)&qv[s][4] = *(const f32x4*)&qs[q][s * 32 + eh * 8 + 4];
        }
#pragma unroll
        for (int kt = 0; kt < 3; ++kt) {
            // B = (K*q) as single f16, built in-register
            f16x8 Bf[2];
#pragma unroll
            for (int s = 0; s < 2; ++s) {
                float g8[8];
#pragma unroll
                for (int i = 0; i < 8; ++i) g8[i] = Kreg[kt][s][i] * qv[s][i];
                Bf[s] = pack8_f16(g8);
            }
            f32x4 acc[6];
#pragma unroll
            for (int lt = 0; lt < 6; ++lt) acc[lt] = (f32x4){0.f, 0.f, 0.f, 0.f};
#pragma unroll
            for (int lt = 0; lt < 6; ++lt) {
                acc[lt] = __builtin_amdgcn_mfma_f32_16x16x32_f16(Af[lt][0], Bf[0], acc[lt], 0, 0, 0);
                acc[lt] = __builtin_amdgcn_mfma_f32_16x16x32_f16(Af[lt][1], Bf[1], acc[lt], 0, 0, 0);
            }
            // r_k = sum over this wave's 96 l rows of exp2(score), raw v_exp
            float r0 = 0.f, r1 = 0.f, r2 = 0.f, r3 = 0.f;
#pragma unroll
            for (int lt = 0; lt < 6; ++lt) {
                r0 += __builtin_amdgcn_exp2f(acc[lt][0]);
                r1 += __builtin_amdgcn_exp2f(acc[lt][1]);
                r2 += __builtin_amdgcn_exp2f(acc[lt][2]);
                r3 += __builtin_amdgcn_exp2f(acc[lt][3]);
            }
            float r = (r0 + r1) + (r2 + r3);
            r += __shfl_xor(r, 16, 64);
            r += __shfl_xor(r, 32, 64);
            if (eh == 0) partial[lg][q][kg * 48 + kt * 16 + c] = r;
        }
    }
    __syncthreads();   // all partials written

    // combine lg partials
    for (int id = t; id < QCB * 192; id += 512) {
        const int q = id / 192, k = id - q * 192;
        Wt[q][k] = partial[0][q][k] + partial[1][q][k];
    }
    __syncthreads();

    // Z per q (wave w handles q = w)
    if (w < QCB) {
        const int q = w;
        float z = Wt[q][lane] + Wt[q][lane + 64] + Wt[q][lane + 128];
#pragma unroll
        for (int off = 32; off >= 1; off >>= 1) z += __shfl_xor(z, off, 64);
        if (lane == 0) zinv[q] = 1.f / z;
    }
    __syncthreads();

    // attended: att[q,d] = zinv * sum_k Wt[q][k] * vh[k,d]; split-k over 2 groups
    const int b = bh >> 3, h = bh & 7;
    {
        const int q = t >> 7;          // 0..3
        const int hk = (t >> 6) & 1;   // k-half
        const int d = t & 63;
        const float* vp = vh + (bh * SS + hk * 96) * HD + d;
        float sum = 0.f;
#pragma unroll 4
        for (int k = 0; k < 96; ++k) sum = fmaf(Wt[q][hk * 96 + k], vp[k * HD], sum);
        if (hk) epart[q][d] = sum;
        __syncthreads();
        if (!hk)
            att[(b * SS + qc * QCB + q) * DD + h * HD + d] = (sum + epart[q][d]) * zinv[q];
    }
}

extern "C" void kernel_launch(void* const* d_in, const int* in_sizes, int n_in,
                              void* d_out, int out_size, void* d_ws, size_t ws_size,
                              hipStream_t stream) {
    (void)in_sizes; (void)n_in; (void)out_size; (void)ws_size;
    const float* q    = (const float*)d_in[0];
    const float* k    = (const float*)d_in[1];
    const float* l    = (const float*)d_in[2];
    const float* v    = (const float*)d_in[3];
    const float* Wq   = (const float*)d_in[4];
    const float* Wk   = (const float*)d_in[5];
    const float* Wv   = (const float*)d_in[6];
    const float* Wout = (const float*)d_in[7];
    float* out = (float*)d_out;

    float* ws  = (float*)d_ws;
    float* qhp = ws + 0 * PROJ_N;
    float* khp = ws + 1 * PROJ_N;
    float* lhp = ws + 2 * PROJ_N;
    float* vhp = ws + 3 * PROJ_N;
    float* atp = ws + 4 * PROJ_N;

    proj4_kernel<<<dim3(384 / 64, 512 / 64, 4), 256, 0, stream>>>(
        q, k, l, v, Wq, Wk, Wv, ws);
    attn3d_mfma_kernel<<<dim3(16 * NQC), 512, 0, stream>>>(qhp, khp, lhp, vhp, atp);
    outproj_kernel<<<dim3(384 / 64, 512 / 64), 256, 0, stream>>>(atp, Wout, out);
}

// Round 7
// 95.231 us; speedup vs baseline: 2.0258x; 2.0258x over previous
//
#include <hip/hip_runtime.h>
#include <math.h>

#define BB 2
#define SS 192
#define DD 512
#define HH 8
#define HD 64
#define QCB 4                 // q-rows per block
#define NQC (SS / QCB)        // 48 q-chunks
#define PROJ_N (BB*HH*SS*HD)
#define SCL (0.125f * 1.44269504088896f)   // 1/sqrt(64) * log2(e)

typedef __attribute__((ext_vector_type(8))) short bf16x8;
typedef __attribute__((ext_vector_type(4))) float f32x4;
typedef __attribute__((ext_vector_type(4))) unsigned uint4v;
typedef _Float16 f16x8 __attribute__((ext_vector_type(8)));

__device__ __forceinline__ unsigned cvt_pk_bf16(float a, float b) {
    unsigned r;
    asm("v_cvt_pk_bf16_f32 %0, %1, %2" : "=v"(r) : "v"(a), "v"(b));
    return r;
}
// x[0..7] ~= hi + lo (split-bf16, rel err ~2^-17) -- used by projection GEMMs
__device__ __forceinline__ void split8_pk(const float* x, uint4v& hi, uint4v& lo) {
#pragma unroll
    for (int p = 0; p < 4; ++p) {
        const float a = x[2 * p], b = x[2 * p + 1];
        const unsigned h = cvt_pk_bf16(a, b);
        const float ra = a - __uint_as_float(h << 16);
        const float rb = b - __uint_as_float(h & 0xFFFF0000u);
        hi[p] = h;
        lo[p] = cvt_pk_bf16(ra, rb);
    }
}

// pack 8 f32 -> f16x8 via v_cvt_pkrtz_f16_f32 (hot path)
__device__ __forceinline__ f16x8 pack8_f16(const float* g) {
    uint4v u;
#pragma unroll
    for (int p = 0; p < 4; ++p)
        u[p] = __builtin_bit_cast(unsigned,
                                  __builtin_amdgcn_cvt_pkrtz(g[2 * p], g[2 * p + 1]));
    return __builtin_bit_cast(f16x8, u);
}

// ---------------------------------------------------------------------------
// Split-bf16 MFMA GEMM: y = x @ W^T   (x: M x 512, W: 512 x 512, f32)
// 64x64 tile / block, 256 thr (4 waves, 2x2), BK=32, double-buffered LDS.
// ---------------------------------------------------------------------------
template <int SPLIT>
__device__ __forceinline__ void gemm_mfma_body(const float* __restrict__ x,
                                               const float* __restrict__ W,
                                               float* __restrict__ y) {
    __shared__ short Ahs[2][4 * 64 * 8], Als[2][4 * 64 * 8];
    __shared__ short Bhs[2][4 * 64 * 8], Bls[2][4 * 64 * 8];

    const int t = threadIdx.x;
    const int lane = t & 63, w = t >> 6;
    const int wr = w >> 1, wc = w & 1;
    const int c16 = lane & 15, q4 = lane >> 4;
    const int m0 = blockIdx.x * 64, n0 = blockIdx.y * 64;
    const int sr = t >> 2, scc = t & 3;

    f32x4 acc[2][2];
#pragma unroll
    for (int a = 0; a < 2; ++a)
#pragma unroll
        for (int b = 0; b < 2; ++b) acc[a][b] = (f32x4){0.f, 0.f, 0.f, 0.f};

#define STAGE(kk, bf)                                                              \
    {                                                                              \
        float a8[8], w8[8];                                                        \
        *(f32x4*)&a8[0] = *(const f32x4*)&x[(m0 + sr) * 512 + (kk) + scc * 8];     \
        *(f32x4*)&a8[4] = *(const f32x4*)&x[(m0 + sr) * 512 + (kk) + scc * 8 + 4]; \
        *(f32x4*)&w8[0] = *(const f32x4*)&W[(n0 + sr) * 512 + (kk) + scc * 8];     \
        *(f32x4*)&w8[4] = *(const f32x4*)&W[(n0 + sr) * 512 + (kk) + scc * 8 + 4]; \
        uint4v h, l;                                                               \
        split8_pk(a8, h, l);                                                       \
        *(uint4v*)&Ahs[bf][(scc * 64 + sr) * 8] = h;                               \
        *(uint4v*)&Als[bf][(scc * 64 + sr) * 8] = l;                               \
        split8_pk(w8, h, l);                                                       \
        *(uint4v*)&Bhs[bf][(scc * 64 + sr) * 8] = h;                               \
        *(uint4v*)&Bls[bf][(scc * 64 + sr) * 8] = l;                               \
    }

    STAGE(0, 0)
    for (int s = 0; s < 16; ++s) {
        __syncthreads();
        if (s + 1 < 16) STAGE((s + 1) * 32, (s + 1) & 1)
        const int b = s & 1;
        bf16x8 aH[2], aL[2], bH[2], bL[2];
#pragma unroll
        for (int mt = 0; mt < 2; ++mt) {
            const int row = wr * 32 + mt * 16 + c16;
            aH[mt] = *(const bf16x8*)&Ahs[b][(q4 * 64 + row) * 8];
            aL[mt] = *(const bf16x8*)&Als[b][(q4 * 64 + row) * 8];
        }
#pragma unroll
        for (int nt = 0; nt < 2; ++nt) {
            const int col = wc * 32 + nt * 16 + c16;
            bH[nt] = *(const bf16x8*)&Bhs[b][(q4 * 64 + col) * 8];
            bL[nt] = *(const bf16x8*)&Bls[b][(q4 * 64 + col) * 8];
        }
#pragma unroll
        for (int mt = 0; mt < 2; ++mt)
#pragma unroll
            for (int nt = 0; nt < 2; ++nt) {
                acc[mt][nt] = __builtin_amdgcn_mfma_f32_16x16x32_bf16(aH[mt], bH[nt], acc[mt][nt], 0, 0, 0);
                acc[mt][nt] = __builtin_amdgcn_mfma_f32_16x16x32_bf16(aH[mt], bL[nt], acc[mt][nt], 0, 0, 0);
                acc[mt][nt] = __builtin_amdgcn_mfma_f32_16x16x32_bf16(aL[mt], bH[nt], acc[mt][nt], 0, 0, 0);
            }
    }
#undef STAGE

#pragma unroll
    for (int mt = 0; mt < 2; ++mt)
#pragma unroll
        for (int nt = 0; nt < 2; ++nt)
#pragma unroll
            for (int j = 0; j < 4; ++j) {
                const int n_row = m0 + wr * 32 + mt * 16 + q4 * 4 + j;
                const int col = n0 + wc * 32 + nt * 16 + c16;
                const float v = acc[mt][nt][j];
                if (SPLIT) {
                    const int b = n_row / SS, s2 = n_row % SS;
                    const int h = col >> 6, e = col & 63;
                    y[((b * HH + h) * SS + s2) * HD + e] = v;
                } else {
                    y[n_row * 512 + col] = v;
                }
            }
}

__global__ __launch_bounds__(256) void proj4_kernel(
    const float* __restrict__ xq, const float* __restrict__ xk,
    const float* __restrict__ xl, const float* __restrict__ xv,
    const float* __restrict__ Wq, const float* __restrict__ Wk,
    const float* __restrict__ Wv, float* __restrict__ ws) {
    const int p = blockIdx.z;
    const float* x = (p == 0) ? xq : (p == 1) ? xk : (p == 2) ? xl : xv;
    const float* W = (p == 0) ? Wq : (p == 3) ? Wv : Wk;
    gemm_mfma_body<1>(x, W, ws + p * PROJ_N);
}

__global__ __launch_bounds__(256) void outproj_kernel(
    const float* __restrict__ att, const float* __restrict__ Wout,
    float* __restrict__ out) {
    gemm_mfma_body<0>(att, Wout, out);
}

// ---------------------------------------------------------------------------
// Barrier-free MFMA rank-3 attention, 3 blocks/CU via grid=768.
// Grid 768 = 16 bh x 48 qc (QCB=4). 512 thr = 8 waves (2 lg x 4 kg).
// A = L rows (f16, regs, q-invariant). B = G = K*q built per-lane in regs.
// No barriers in the q loop; raw v_exp_f32; stats via one end barrier.
// NOTE: no min-waves clamp -- __launch_bounds__(512,6) forced VGPR 80->40
// and spilled the whole working set to scratch (FETCH_SIZE 9.6MB->413MB).
// ---------------------------------------------------------------------------
__global__ __launch_bounds__(512) void attn3d_mfma_kernel(
    const float* __restrict__ qh, const float* __restrict__ kh,
    const float* __restrict__ lh, const float* __restrict__ vh,
    float* __restrict__ att) {
    __shared__ float qs[QCB][64];          // 1 KB
    __shared__ float partial[2][QCB][192]; // 6 KB
    __shared__ float Wt[QCB][192];         // 3 KB
    __shared__ float epart[QCB][64];       // 1 KB
    __shared__ float zinv[QCB];

    const int blk = blockIdx.x;
    const int bh = blk / NQC, qc = blk - bh * NQC;
    const int t = threadIdx.x;
    const int lane = t & 63, w = t >> 6;
    const int lg = w >> 2, kg = w & 3;
    const int c = lane & 15, eh = lane >> 4;

    // stage q rows (scale+log2e folded)
    if (t < QCB * 64) {
        const int q = t >> 6, e = t & 63;
        qs[q][e] = qh[(bh * SS + qc * QCB + q) * HD + e] * SCL;
    }

    // K slice in registers: col = kg*48+kt*16+c, e = s*32+eh*8..
    float Kreg[3][2][8];
#pragma unroll
    for (int kt = 0; kt < 3; ++kt)
#pragma unroll
        for (int s = 0; s < 2; ++s) {
            const int col = kg * 48 + kt * 16 + c;
            const float* kp = &kh[(bh * SS + col) * HD + s * 32 + eh * 8];
            *(f32x4*)&Kreg[kt][s][0] = *(const f32x4*)&kp[0];
            *(f32x4*)&Kreg[kt][s][4] = *(const f32x4*)&kp[4];
        }

    // A fragments: L rows as single f16 (RTZ pack), q-invariant
    f16x8 Af[6][2];
#pragma unroll
    for (int lt = 0; lt < 6; ++lt)
#pragma unroll
        for (int s = 0; s < 2; ++s) {
            const int row = lg * 96 + lt * 16 + c;
            float buf8[8];
            const float* lp = &lh[(bh * SS + row) * HD + s * 32 + eh * 8];
            *(f32x4*)&buf8[0] = *(const f32x4*)&lp[0];
            *(f32x4*)&buf8[4] = *(const f32x4*)&lp[4];
            Af[lt][s] = pack8_f16(buf8);
        }
    __syncthreads();   // qs ready

    // ---- barrier-free q loop ----
    for (int q = 0; q < QCB; ++q) {
        float qv[2][8];
#pragma unroll
        for (int s = 0; s < 2; ++s) {
            *(f32x4*)&qv[s][0] = *(const f32x4*)&qs[q][s * 32 + eh * 8];
            *(f32x4*)&qv[s][4] = *(const f32x4*)&qs[q][s * 32 + eh * 8 + 4];
        }
#pragma unroll
        for (int kt = 0; kt < 3; ++kt) {
            // B = (K*q) as single f16, built in-register
            f16x8 Bf[2];
#pragma unroll
            for (int s = 0; s < 2; ++s) {
                float g8[8];
#pragma unroll
                for (int i = 0; i < 8; ++i) g8[i] = Kreg[kt][s][i] * qv[s][i];
                Bf[s] = pack8_f16(g8);
            }
            f32x4 acc[6];
#pragma unroll
            for (int lt = 0; lt < 6; ++lt) acc[lt] = (f32x4){0.f, 0.f, 0.f, 0.f};
#pragma unroll
            for (int lt = 0; lt < 6; ++lt) {
                acc[lt] = __builtin_amdgcn_mfma_f32_16x16x32_f16(Af[lt][0], Bf[0], acc[lt], 0, 0, 0);
                acc[lt] = __builtin_amdgcn_mfma_f32_16x16x32_f16(Af[lt][1], Bf[1], acc[lt], 0, 0, 0);
            }
            // r_k = sum over this wave's 96 l rows of exp2(score), raw v_exp
            float r0 = 0.f, r1 = 0.f, r2 = 0.f, r3 = 0.f;
#pragma unroll
            for (int lt = 0; lt < 6; ++lt) {
                r0 += __builtin_amdgcn_exp2f(acc[lt][0]);
                r1 += __builtin_amdgcn_exp2f(acc[lt][1]);
                r2 += __builtin_amdgcn_exp2f(acc[lt][2]);
                r3 += __builtin_amdgcn_exp2f(acc[lt][3]);
            }
            float r = (r0 + r1) + (r2 + r3);
            r += __shfl_xor(r, 16, 64);
            r += __shfl_xor(r, 32, 64);
            if (eh == 0) partial[lg][q][kg * 48 + kt * 16 + c] = r;
        }
    }
    __syncthreads();   // all partials written

    // combine lg partials
    for (int id = t; id < QCB * 192; id += 512) {
        const int q = id / 192, k = id - q * 192;
        Wt[q][k] = partial[0][q][k] + partial[1][q][k];
    }
    __syncthreads();

    // Z per q (wave w handles q = w)
    if (w < QCB) {
        const int q = w;
        float z = Wt[q][lane] + Wt[q][lane + 64] + Wt[q][lane + 128];
#pragma unroll
        for (int off = 32; off >= 1; off >>= 1) z += __shfl_xor(z, off, 64);
        if (lane == 0) zinv[q] = 1.f / z;
    }
    __syncthreads();

    // attended: att[q,d] = zinv * sum_k Wt[q][k] * vh[k,d]; split-k over 2 groups
    const int b = bh >> 3, h = bh & 7;
    {
        const int q = t >> 7;          // 0..3
        const int hk = (t >> 6) & 1;   // k-half
        const int d = t & 63;
        const float* vp = vh + (bh * SS + hk * 96) * HD + d;
        float sum = 0.f;
#pragma unroll 4
        for (int k = 0; k < 96; ++k) sum = fmaf(Wt[q][hk * 96 + k], vp[k * HD], sum);
        if (hk) epart[q][d] = sum;
        __syncthreads();
        if (!hk)
            att[(b * SS + qc * QCB + q) * DD + h * HD + d] = (sum + epart[q][d]) * zinv[q];
    }
}

extern "C" void kernel_launch(void* const* d_in, const int* in_sizes, int n_in,
                              void* d_out, int out_size, void* d_ws, size_t ws_size,
                              hipStream_t stream) {
    (void)in_sizes; (void)n_in; (void)out_size; (void)ws_size;
    const float* q    = (const float*)d_in[0];
    const float* k    = (const float*)d_in[1];
    const float* l    = (const float*)d_in[2];
    const float* v    = (const float*)d_in[3];
    const float* Wq   = (const float*)d_in[4];
    const float* Wk   = (const float*)d_in[5];
    const float* Wv   = (const float*)d_in[6];
    const float* Wout = (const float*)d_in[7];
    float* out = (float*)d_out;

    float* ws  = (float*)d_ws;
    float* qhp = ws + 0 * PROJ_N;
    float* khp = ws + 1 * PROJ_N;
    float* lhp = ws + 2 * PROJ_N;
    float* vhp = ws + 3 * PROJ_N;
    float* atp = ws + 4 * PROJ_N;

    proj4_kernel<<<dim3(384 / 64, 512 / 64, 4), 256, 0, stream>>>(
        q, k, l, v, Wq, Wk, Wv, ws);
    attn3d_mfma_kernel<<<dim3(16 * NQC), 512, 0, stream>>>(qhp, khp, lhp, vhp, atp);
    outproj_kernel<<<dim3(384 / 64, 512 / 64), 256, 0, stream>>>(atp, Wout, out);
}

// Round 8
// 86.726 us; speedup vs baseline: 2.2244x; 1.0981x over previous
//
#include <hip/hip_runtime.h>
#include <math.h>

#define BB 2
#define SS 192
#define DD 512
#define HH 8
#define HD 64
#define QCB 6                 // q-rows per block
#define NQC (SS / QCB)        // 32 q-chunks
#define PROJ_N (BB*HH*SS*HD)
#define SCL (0.125f * 1.44269504088896f)   // 1/sqrt(64) * log2(e)

typedef __attribute__((ext_vector_type(8))) short bf16x8;
typedef __attribute__((ext_vector_type(4))) float f32x4;
typedef __attribute__((ext_vector_type(4))) unsigned uint4v;
typedef _Float16 f16x8 __attribute__((ext_vector_type(8)));

__device__ __forceinline__ unsigned cvt_pk_bf16(float a, float b) {
    unsigned r;
    asm("v_cvt_pk_bf16_f32 %0, %1, %2" : "=v"(r) : "v"(a), "v"(b));
    return r;
}
// x[0..7] ~= hi + lo (split-bf16) -- used by projection GEMMs
__device__ __forceinline__ void split8_pk(const float* x, uint4v& hi, uint4v& lo) {
#pragma unroll
    for (int p = 0; p < 4; ++p) {
        const float a = x[2 * p], b = x[2 * p + 1];
        const unsigned h = cvt_pk_bf16(a, b);
        const float ra = a - __uint_as_float(h << 16);
        const float rb = b - __uint_as_float(h & 0xFFFF0000u);
        hi[p] = h;
        lo[p] = cvt_pk_bf16(ra, rb);
    }
}

// 8 f32 -> f16x8, RNE (v_cvt_f16_f32)
__device__ __forceinline__ f16x8 cvt8_f16_rne(const float* g) {
    f16x8 r;
#pragma unroll
    for (int i = 0; i < 8; ++i) r[i] = (_Float16)g[i];
    return r;
}

// ---------------------------------------------------------------------------
// Split-bf16 MFMA GEMM: y = x @ W^T   (x: M x 512, W: 512 x 512, f32)
// ---------------------------------------------------------------------------
template <int SPLIT>
__device__ __forceinline__ void gemm_mfma_body(const float* __restrict__ x,
                                               const float* __restrict__ W,
                                               float* __restrict__ y) {
    __shared__ short Ahs[2][4 * 64 * 8], Als[2][4 * 64 * 8];
    __shared__ short Bhs[2][4 * 64 * 8], Bls[2][4 * 64 * 8];

    const int t = threadIdx.x;
    const int lane = t & 63, w = t >> 6;
    const int wr = w >> 1, wc = w & 1;
    const int c16 = lane & 15, q4 = lane >> 4;
    const int m0 = blockIdx.x * 64, n0 = blockIdx.y * 64;
    const int sr = t >> 2, scc = t & 3;

    f32x4 acc[2][2];
#pragma unroll
    for (int a = 0; a < 2; ++a)
#pragma unroll
        for (int b = 0; b < 2; ++b) acc[a][b] = (f32x4){0.f, 0.f, 0.f, 0.f};

#define STAGE(kk, bf)                                                              \
    {                                                                              \
        float a8[8], w8[8];                                                        \
        *(f32x4*)&a8[0] = *(const f32x4*)&x[(m0 + sr) * 512 + (kk) + scc * 8];     \
        *(f32x4*)&a8[4] = *(const f32x4*)&x[(m0 + sr) * 512 + (kk) + scc * 8 + 4]; \
        *(f32x4*)&w8[0] = *(const f32x4*)&W[(n0 + sr) * 512 + (kk) + scc * 8];     \
        *(f32x4*)&w8[4] = *(const f32x4*)&W[(n0 + sr) * 512 + (kk) + scc * 8 + 4]; \
        uint4v h, l;                                                               \
        split8_pk(a8, h, l);                                                       \
        *(uint4v*)&Ahs[bf][(scc * 64 + sr) * 8] = h;                               \
        *(uint4v*)&Als[bf][(scc * 64 + sr) * 8] = l;                               \
        split8_pk(w8, h, l);                                                       \
        *(uint4v*)&Bhs[bf][(scc * 64 + sr) * 8] = h;                               \
        *(uint4v*)&Bls[bf][(scc * 64 + sr) * 8] = l;                               \
    }

    STAGE(0, 0)
    for (int s = 0; s < 16; ++s) {
        __syncthreads();
        if (s + 1 < 16) STAGE((s + 1) * 32, (s + 1) & 1)
        const int b = s & 1;
        bf16x8 aH[2], aL[2], bH[2], bL[2];
#pragma unroll
        for (int mt = 0; mt < 2; ++mt) {
            const int row = wr * 32 + mt * 16 + c16;
            aH[mt] = *(const bf16x8*)&Ahs[b][(q4 * 64 + row) * 8];
            aL[mt] = *(const bf16x8*)&Als[b][(q4 * 64 + row) * 8];
        }
#pragma unroll
        for (int nt = 0; nt < 2; ++nt) {
            const int col = wc * 32 + nt * 16 + c16;
            bH[nt] = *(const bf16x8*)&Bhs[b][(q4 * 64 + col) * 8];
            bL[nt] = *(const bf16x8*)&Bls[b][(q4 * 64 + col) * 8];
        }
#pragma unroll
        for (int mt = 0; mt < 2; ++mt)
#pragma unroll
            for (int nt = 0; nt < 2; ++nt) {
                acc[mt][nt] = __builtin_amdgcn_mfma_f32_16x16x32_bf16(aH[mt], bH[nt], acc[mt][nt], 0, 0, 0);
                acc[mt][nt] = __builtin_amdgcn_mfma_f32_16x16x32_bf16(aH[mt], bL[nt], acc[mt][nt], 0, 0, 0);
                acc[mt][nt] = __builtin_amdgcn_mfma_f32_16x16x32_bf16(aL[mt], bH[nt], acc[mt][nt], 0, 0, 0);
            }
    }
#undef STAGE

#pragma unroll
    for (int mt = 0; mt < 2; ++mt)
#pragma unroll
        for (int nt = 0; nt < 2; ++nt)
#pragma unroll
            for (int j = 0; j < 4; ++j) {
                const int n_row = m0 + wr * 32 + mt * 16 + q4 * 4 + j;
                const int col = n0 + wc * 32 + nt * 16 + c16;
                const float v = acc[mt][nt][j];
                if (SPLIT) {
                    const int b = n_row / SS, s2 = n_row % SS;
                    const int h = col >> 6, e = col & 63;
                    y[((b * HH + h) * SS + s2) * HD + e] = v;
                } else {
                    y[n_row * 512 + col] = v;
                }
            }
}

__global__ __launch_bounds__(256) void proj4_kernel(
    const float* __restrict__ xq, const float* __restrict__ xk,
    const float* __restrict__ xl, const float* __restrict__ xv,
    const float* __restrict__ Wq, const float* __restrict__ Wk,
    const float* __restrict__ Wv, float* __restrict__ ws) {
    const int p = blockIdx.z;
    const float* x = (p == 0) ? xq : (p == 1) ? xk : (p == 2) ? xl : xv;
    const float* W = (p == 0) ? Wq : (p == 3) ? Wv : Wk;
    gemm_mfma_body<1>(x, W, ws + p * PROJ_N);
}

__global__ __launch_bounds__(256) void outproj_kernel(
    const float* __restrict__ att, const float* __restrict__ Wout,
    float* __restrict__ out) {
    gemm_mfma_body<0>(att, Wout, out);
}

// ---------------------------------------------------------------------------
// Slim-wave barrier-free MFMA rank-3 attention.
// Grid 512 = 16 bh x 32 qc (QCB=6) = exactly 2 blocks/CU. 8 waves (2lg x 4kg).
// A = L rows f16 in regs (48 VGPR). K f16 frag-major in LDS (pad-193 planes);
// B = K*q via ds_read_b128 + v_pk_mul_f16 vs broadcast f16 q-frag -> transient
// regs only. Target: arch VGPR ~100 (<128 class) so 2 blocks/CU co-reside.
// ---------------------------------------------------------------------------
__global__ __launch_bounds__(512) void attn3d_mfma_kernel(
    const float* __restrict__ qh, const float* __restrict__ kh,
    const float* __restrict__ lh, const float* __restrict__ vh,
    float* __restrict__ att) {
    __shared__ short Kf16[8][193][8];      // [ec][k(+pad)][8] f16: 24.7 KB
    __shared__ short qpk[QCB][8][8];       // [q][ec][8] f16: 768 B
    __shared__ float partial[2][QCB][192]; // [lg][q][k]: 9 KB
    __shared__ float Wt[QCB][192];         // 4.5 KB
    __shared__ float zinv[QCB];

    const int blk = blockIdx.x;
    const int bh = blk >> 5, qc = blk & 31;
    const int t = threadIdx.x;
    const int lane = t & 63, w = t >> 6;
    const int lg = w >> 2, kg = w & 3;
    const int c = lane & 15, eh = lane >> 4;

    // ---- stage q rows as f16 (scale+log2e folded) ----
    if (t < QCB * 64) {
        const int q = t >> 6, e = t & 63;
        const float v = qh[(bh * SS + qc * QCB + q) * HD + e] * SCL;
        qpk[q][e >> 3][e & 7] = __builtin_bit_cast(short, (_Float16)v);
    }
    // ---- stage K as f16 frag-major (coalesced global reads) ----
#pragma unroll
    for (int j = 0; j < 3; ++j) {
        const int cid = t + 512 * j;          // 1536 8-elem chunks
        const int k = cid >> 3, ec = cid & 7;
        float b8[8];
        const float* kp = &kh[(bh * SS + k) * HD + ec * 8];
        *(f32x4*)&b8[0] = *(const f32x4*)&kp[0];
        *(f32x4*)&b8[4] = *(const f32x4*)&kp[4];
        *(f16x8*)&Kf16[ec][k][0] = cvt8_f16_rne(b8);
    }
    // ---- A fragments: L rows f16 RNE, q-invariant, in registers ----
    f16x8 Af[6][2];
#pragma unroll
    for (int lt = 0; lt < 6; ++lt)
#pragma unroll
        for (int s = 0; s < 2; ++s) {
            const int row = lg * 96 + lt * 16 + c;
            float b8[8];
            const float* lp = &lh[(bh * SS + row) * HD + s * 32 + eh * 8];
            *(f32x4*)&b8[0] = *(const f32x4*)&lp[0];
            *(f32x4*)&b8[4] = *(const f32x4*)&lp[4];
            Af[lt][s] = cvt8_f16_rne(b8);
        }
    __syncthreads();   // qpk, Kf16 ready

    // ---- barrier-free q loop ----
    for (int q = 0; q < QCB; ++q) {
        f16x8 qf[2];
#pragma unroll
        for (int s = 0; s < 2; ++s)
            qf[s] = *(const f16x8*)&qpk[q][s * 4 + eh][0];   // broadcast
#pragma unroll
        for (int kt = 0; kt < 3; ++kt) {
            const int col = kg * 48 + kt * 16 + c;
            f16x8 Bf[2];
#pragma unroll
            for (int s = 0; s < 2; ++s) {
                const f16x8 Kf = *(const f16x8*)&Kf16[s * 4 + eh][col][0];
                Bf[s] = Kf * qf[s];                          // 4 v_pk_mul_f16
            }
            f32x4 acc[6];
#pragma unroll
            for (int lt = 0; lt < 6; ++lt) acc[lt] = (f32x4){0.f, 0.f, 0.f, 0.f};
#pragma unroll
            for (int lt = 0; lt < 6; ++lt) {
                acc[lt] = __builtin_amdgcn_mfma_f32_16x16x32_f16(Af[lt][0], Bf[0], acc[lt], 0, 0, 0);
                acc[lt] = __builtin_amdgcn_mfma_f32_16x16x32_f16(Af[lt][1], Bf[1], acc[lt], 0, 0, 0);
            }
            // r_k = sum over this wave's 96 l rows of exp2(score)
            float r0 = 0.f, r1 = 0.f, r2 = 0.f, r3 = 0.f;
#pragma unroll
            for (int lt = 0; lt < 6; ++lt) {
                r0 += __builtin_amdgcn_exp2f(acc[lt][0]);
                r1 += __builtin_amdgcn_exp2f(acc[lt][1]);
                r2 += __builtin_amdgcn_exp2f(acc[lt][2]);
                r3 += __builtin_amdgcn_exp2f(acc[lt][3]);
            }
            float r = (r0 + r1) + (r2 + r3);
            r += __shfl_xor(r, 16, 64);
            r += __shfl_xor(r, 32, 64);
            if (eh == 0) partial[lg][q][col] = r;
        }
    }
    __syncthreads();   // all partials written

    // combine lg partials
    for (int id = t; id < QCB * 192; id += 512) {
        const int q = id / 192, k = id - q * 192;
        Wt[q][k] = partial[0][q][k] + partial[1][q][k];
    }
    __syncthreads();

    // Z per q (wave w handles q = w)
    if (w < QCB) {
        const int q = w;
        float z = Wt[q][lane] + Wt[q][lane + 64] + Wt[q][lane + 128];
#pragma unroll
        for (int off = 32; off >= 1; off >>= 1) z += __shfl_xor(z, off, 64);
        if (lane == 0) zinv[q] = 1.f / z;
    }
    __syncthreads();

    // attended: att[q,d] = zinv * sum_k Wt[q][k] * vh[k,d]
    const int b = bh >> 3, h = bh & 7;
    if (t < QCB * 64) {
        const int q = t >> 6, d = t & 63;
        const float* vp = vh + bh * SS * HD + d;
        float sum = 0.f;
#pragma unroll 4
        for (int k = 0; k < SS; ++k) sum = fmaf(Wt[q][k], vp[k * HD], sum);
        att[(b * SS + qc * QCB + q) * DD + h * HD + d] = sum * zinv[q];
    }
}

extern "C" void kernel_launch(void* const* d_in, const int* in_sizes, int n_in,
                              void* d_out, int out_size, void* d_ws, size_t ws_size,
                              hipStream_t stream) {
    (void)in_sizes; (void)n_in; (void)out_size; (void)ws_size;
    const float* q    = (const float*)d_in[0];
    const float* k    = (const float*)d_in[1];
    const float* l    = (const float*)d_in[2];
    const float* v    = (const float*)d_in[3];
    const float* Wq   = (const float*)d_in[4];
    const float* Wk   = (const float*)d_in[5];
    const float* Wv   = (const float*)d_in[6];
    const float* Wout = (const float*)d_in[7];
    float* out = (float*)d_out;

    float* ws  = (float*)d_ws;
    float* qhp = ws + 0 * PROJ_N;
    float* khp = ws + 1 * PROJ_N;
    float* lhp = ws + 2 * PROJ_N;
    float* vhp = ws + 3 * PROJ_N;
    float* atp = ws + 4 * PROJ_N;

    proj4_kernel<<<dim3(384 / 64, 512 / 64, 4), 256, 0, stream>>>(
        q, k, l, v, Wq, Wk, Wv, ws);
    attn3d_mfma_kernel<<<dim3(16 * NQC), 512, 0, stream>>>(qhp, khp, lhp, vhp, atp);
    outproj_kernel<<<dim3(384 / 64, 512 / 64), 256, 0, stream>>>(atp, Wout, out);
}

// Round 9
// 66.836 us; speedup vs baseline: 2.8864x; 1.2976x over previous
//
#include <hip/hip_runtime.h>
#include <math.h>

#define BB 2
#define SS 192
#define DD 512
#define HH 8
#define HD 64
#define QCB 6                 // q-rows per block
#define NQC (SS / QCB)        // 32 q-chunks
#define PROJ_N (BB*HH*SS*HD)
#define SCL (0.125f * 1.44269504088896f)   // 1/sqrt(64) * log2(e)

typedef __attribute__((ext_vector_type(8))) short bf16x8;
typedef __attribute__((ext_vector_type(4))) float f32x4;
typedef __attribute__((ext_vector_type(4))) unsigned uint4v;
typedef _Float16 f16x8 __attribute__((ext_vector_type(8)));

__device__ __forceinline__ unsigned cvt_pk_bf16(float a, float b) {
    unsigned r;
    asm("v_cvt_pk_bf16_f32 %0, %1, %2" : "=v"(r) : "v"(a), "v"(b));
    return r;
}
// x[0..7] ~= hi + lo (split-bf16) -- used by projection GEMMs
__device__ __forceinline__ void split8_pk(const float* x, uint4v& hi, uint4v& lo) {
#pragma unroll
    for (int p = 0; p < 4; ++p) {
        const float a = x[2 * p], b = x[2 * p + 1];
        const unsigned h = cvt_pk_bf16(a, b);
        const float ra = a - __uint_as_float(h << 16);
        const float rb = b - __uint_as_float(h & 0xFFFF0000u);
        hi[p] = h;
        lo[p] = cvt_pk_bf16(ra, rb);
    }
}

// 8 f32 -> f16x8, RNE (v_cvt_f16_f32)
__device__ __forceinline__ f16x8 cvt8_f16_rne(const float* g) {
    f16x8 r;
#pragma unroll
    for (int i = 0; i < 8; ++i) r[i] = (_Float16)g[i];
    return r;
}

// ---------------------------------------------------------------------------
// Split-bf16 MFMA GEMM: y = x @ W^T   (x: M x 512, W: 512 x 512, f32)
// ---------------------------------------------------------------------------
template <int SPLIT>
__device__ __forceinline__ void gemm_mfma_body(const float* __restrict__ x,
                                               const float* __restrict__ W,
                                               float* __restrict__ y) {
    __shared__ short Ahs[2][4 * 64 * 8], Als[2][4 * 64 * 8];
    __shared__ short Bhs[2][4 * 64 * 8], Bls[2][4 * 64 * 8];

    const int t = threadIdx.x;
    const int lane = t & 63, w = t >> 6;
    const int wr = w >> 1, wc = w & 1;
    const int c16 = lane & 15, q4 = lane >> 4;
    const int m0 = blockIdx.x * 64, n0 = blockIdx.y * 64;
    const int sr = t >> 2, scc = t & 3;

    f32x4 acc[2][2];
#pragma unroll
    for (int a = 0; a < 2; ++a)
#pragma unroll
        for (int b = 0; b < 2; ++b) acc[a][b] = (f32x4){0.f, 0.f, 0.f, 0.f};

#define STAGE(kk, bf)                                                              \
    {                                                                              \
        float a8[8], w8[8];                                                        \
        *(f32x4*)&a8[0] = *(const f32x4*)&x[(m0 + sr) * 512 + (kk) + scc * 8];     \
        *(f32x4*)&a8[4] = *(const f32x4*)&x[(m0 + sr) * 512 + (kk) + scc * 8 + 4]; \
        *(f32x4*)&w8[0] = *(const f32x4*)&W[(n0 + sr) * 512 + (kk) + scc * 8];     \
        *(f32x4*)&w8[4] = *(const f32x4*)&W[(n0 + sr) * 512 + (kk) + scc * 8 + 4]; \
        uint4v h, l;                                                               \
        split8_pk(a8, h, l);                                                       \
        *(uint4v*)&Ahs[bf][(scc * 64 + sr) * 8] = h;                               \
        *(uint4v*)&Als[bf][(scc * 64 + sr) * 8] = l;                               \
        split8_pk(w8, h, l);                                                       \
        *(uint4v*)&Bhs[bf][(scc * 64 + sr) * 8] = h;                               \
        *(uint4v*)&Bls[bf][(scc * 64 + sr) * 8] = l;                               \
    }

    STAGE(0, 0)
    for (int s = 0; s < 16; ++s) {
        __syncthreads();
        if (s + 1 < 16) STAGE((s + 1) * 32, (s + 1) & 1)
        const int b = s & 1;
        bf16x8 aH[2], aL[2], bH[2], bL[2];
#pragma unroll
        for (int mt = 0; mt < 2; ++mt) {
            const int row = wr * 32 + mt * 16 + c16;
            aH[mt] = *(const bf16x8*)&Ahs[b][(q4 * 64 + row) * 8];
            aL[mt] = *(const bf16x8*)&Als[b][(q4 * 64 + row) * 8];
        }
#pragma unroll
        for (int nt = 0; nt < 2; ++nt) {
            const int col = wc * 32 + nt * 16 + c16;
            bH[nt] = *(const bf16x8*)&Bhs[b][(q4 * 64 + col) * 8];
            bL[nt] = *(const bf16x8*)&Bls[b][(q4 * 64 + col) * 8];
        }
#pragma unroll
        for (int mt = 0; mt < 2; ++mt)
#pragma unroll
            for (int nt = 0; nt < 2; ++nt) {
                acc[mt][nt] = __builtin_amdgcn_mfma_f32_16x16x32_bf16(aH[mt], bH[nt], acc[mt][nt], 0, 0, 0);
                acc[mt][nt] = __builtin_amdgcn_mfma_f32_16x16x32_bf16(aH[mt], bL[nt], acc[mt][nt], 0, 0, 0);
                acc[mt][nt] = __builtin_amdgcn_mfma_f32_16x16x32_bf16(aL[mt], bH[nt], acc[mt][nt], 0, 0, 0);
            }
    }
#undef STAGE

#pragma unroll
    for (int mt = 0; mt < 2; ++mt)
#pragma unroll
        for (int nt = 0; nt < 2; ++nt)
#pragma unroll
            for (int j = 0; j < 4; ++j) {
                const int n_row = m0 + wr * 32 + mt * 16 + q4 * 4 + j;
                const int col = n0 + wc * 32 + nt * 16 + c16;
                const float v = acc[mt][nt][j];
                if (SPLIT) {
                    const int b = n_row / SS, s2 = n_row % SS;
                    const int h = col >> 6, e = col & 63;
                    y[((b * HH + h) * SS + s2) * HD + e] = v;
                } else {
                    y[n_row * 512 + col] = v;
                }
            }
}

__global__ __launch_bounds__(256) void proj4_kernel(
    const float* __restrict__ xq, const float* __restrict__ xk,
    const float* __restrict__ xl, const float* __restrict__ xv,
    const float* __restrict__ Wq, const float* __restrict__ Wk,
    const float* __restrict__ Wv, float* __restrict__ ws) {
    const int p = blockIdx.z;
    const float* x = (p == 0) ? xq : (p == 1) ? xk : (p == 2) ? xl : xv;
    const float* W = (p == 0) ? Wq : (p == 3) ? Wv : Wk;
    gemm_mfma_body<1>(x, W, ws + p * PROJ_N);
}

__global__ __launch_bounds__(256) void outproj_kernel(
    const float* __restrict__ att, const float* __restrict__ Wout,
    float* __restrict__ out) {
    gemm_mfma_body<0>(att, Wout, out);
}

// ---------------------------------------------------------------------------
// Shuffle-free barrier-free MFMA rank-3 attention.
// Grid 512 = 16 bh x 32 qc (QCB=6). 512 thr = 8 waves (2 lg x 4 kg).
// Hot loop per (q,kt): B = K*q (f16, LDS-read + pk_mul), 12 MFMA, 24 exp.
// NO cross-lane shuffles: each lane's per-eh partial sum-exp goes straight
// to part4[q][lg][eh][col] (3 ds_write/q); one bulk combine after the end
// barrier. Removes the ~240cyc/iter serial ds_bpermute chain of R8.
// ---------------------------------------------------------------------------
__global__ __launch_bounds__(512) void attn3d_mfma_kernel(
    const float* __restrict__ qh, const float* __restrict__ kh,
    const float* __restrict__ lh, const float* __restrict__ vh,
    float* __restrict__ att) {
    __shared__ short Kf16[8][193][8];        // [ec][k(+pad)][8] f16: 24.7 KB
    __shared__ short qpk[QCB][8][8];         // [q][ec][8] f16: 768 B
    __shared__ float part4[QCB][2][4][193];  // [q][lg][eh][k(+pad)]: 37.1 KB
    __shared__ float Wt[QCB][192];           // 4.6 KB
    __shared__ float zinv[QCB];

    const int blk = blockIdx.x;
    const int bh = blk >> 5, qc = blk & 31;
    const int t = threadIdx.x;
    const int lane = t & 63, w = t >> 6;
    const int lg = w >> 2, kg = w & 3;
    const int c = lane & 15, eh = lane >> 4;

    // ---- stage q rows as f16 (scale+log2e folded) ----
    if (t < QCB * 64) {
        const int q = t >> 6, e = t & 63;
        const float v = qh[(bh * SS + qc * QCB + q) * HD + e] * SCL;
        qpk[q][e >> 3][e & 7] = __builtin_bit_cast(short, (_Float16)v);
    }
    // ---- stage K as f16 frag-major (coalesced global reads) ----
#pragma unroll
    for (int j = 0; j < 3; ++j) {
        const int cid = t + 512 * j;          // 1536 8-elem chunks
        const int k = cid >> 3, ec = cid & 7;
        float b8[8];
        const float* kp = &kh[(bh * SS + k) * HD + ec * 8];
        *(f32x4*)&b8[0] = *(const f32x4*)&kp[0];
        *(f32x4*)&b8[4] = *(const f32x4*)&kp[4];
        *(f16x8*)&Kf16[ec][k][0] = cvt8_f16_rne(b8);
    }
    // ---- A fragments: L rows f16 RNE, q-invariant, in registers ----
    f16x8 Af[6][2];
#pragma unroll
    for (int lt = 0; lt < 6; ++lt)
#pragma unroll
        for (int s = 0; s < 2; ++s) {
            const int row = lg * 96 + lt * 16 + c;
            float b8[8];
            const float* lp = &lh[(bh * SS + row) * HD + s * 32 + eh * 8];
            *(f32x4*)&b8[0] = *(const f32x4*)&lp[0];
            *(f32x4*)&b8[4] = *(const f32x4*)&lp[4];
            Af[lt][s] = cvt8_f16_rne(b8);
        }
    __syncthreads();   // qpk, Kf16 ready

    // ---- barrier-free, shuffle-free q loop ----
    for (int q = 0; q < QCB; ++q) {
        f16x8 qf[2];
#pragma unroll
        for (int s = 0; s < 2; ++s)
            qf[s] = *(const f16x8*)&qpk[q][s * 4 + eh][0];   // broadcast
        float rq[3];
#pragma unroll
        for (int kt = 0; kt < 3; ++kt) {
            const int col = kg * 48 + kt * 16 + c;
            f16x8 Bf[2];
#pragma unroll
            for (int s = 0; s < 2; ++s) {
                const f16x8 Kf = *(const f16x8*)&Kf16[s * 4 + eh][col][0];
                Bf[s] = Kf * qf[s];                          // 4 v_pk_mul_f16
            }
            f32x4 acc[6];
#pragma unroll
            for (int lt = 0; lt < 6; ++lt) acc[lt] = (f32x4){0.f, 0.f, 0.f, 0.f};
#pragma unroll
            for (int lt = 0; lt < 6; ++lt) {
                acc[lt] = __builtin_amdgcn_mfma_f32_16x16x32_f16(Af[lt][0], Bf[0], acc[lt], 0, 0, 0);
                acc[lt] = __builtin_amdgcn_mfma_f32_16x16x32_f16(Af[lt][1], Bf[1], acc[lt], 0, 0, 0);
            }
            // per-lane (per-eh) partial: sum of exp2 over this lane's 24 l rows
            float r0 = 0.f, r1 = 0.f, r2 = 0.f, r3 = 0.f;
#pragma unroll
            for (int lt = 0; lt < 6; ++lt) {
                r0 += __builtin_amdgcn_exp2f(acc[lt][0]);
                r1 += __builtin_amdgcn_exp2f(acc[lt][1]);
                r2 += __builtin_amdgcn_exp2f(acc[lt][2]);
                r3 += __builtin_amdgcn_exp2f(acc[lt][3]);
            }
            rq[kt] = (r0 + r1) + (r2 + r3);
        }
        // 3 scattered-but-bank-spread LDS stores; no cross-lane ops
#pragma unroll
        for (int kt = 0; kt < 3; ++kt)
            part4[q][lg][eh][kg * 48 + kt * 16 + c] = rq[kt];
    }
    __syncthreads();   // all partials written

    // bulk combine: Wt[q][k] = sum over 2 lg x 4 eh
    for (int id = t; id < QCB * 192; id += 512) {
        const int q = id / 192, k = id - q * 192;
        float s0 = 0.f;
#pragma unroll
        for (int lg2 = 0; lg2 < 2; ++lg2)
#pragma unroll
            for (int e2 = 0; e2 < 4; ++e2) s0 += part4[q][lg2][e2][k];
        Wt[q][k] = s0;
    }
    __syncthreads();

    // Z per q (wave w handles q = w)
    if (w < QCB) {
        const int q = w;
        float z = Wt[q][lane] + Wt[q][lane + 64] + Wt[q][lane + 128];
#pragma unroll
        for (int off = 32; off >= 1; off >>= 1) z += __shfl_xor(z, off, 64);
        if (lane == 0) zinv[q] = 1.f / z;
    }
    __syncthreads();

    // attended: att[q,d] = zinv * sum_k Wt[q][k] * vh[k,d]; 8 loads in flight
    const int b = bh >> 3, h = bh & 7;
    if (t < QCB * 64) {
        const int q = t >> 6, d = t & 63;
        const float* vp = vh + bh * SS * HD + d;
        float sum = 0.f;
        for (int k0 = 0; k0 < SS; k0 += 8) {
            float v8[8];
#pragma unroll
            for (int j = 0; j < 8; ++j) v8[j] = vp[(k0 + j) * HD];
#pragma unroll
            for (int j = 0; j < 8; ++j) sum = fmaf(Wt[q][k0 + j], v8[j], sum);
        }
        att[(b * SS + qc * QCB + q) * DD + h * HD + d] = sum * zinv[q];
    }
}

extern "C" void kernel_launch(void* const* d_in, const int* in_sizes, int n_in,
                              void* d_out, int out_size, void* d_ws, size_t ws_size,
                              hipStream_t stream) {
    (void)in_sizes; (void)n_in; (void)out_size; (void)ws_size;
    const float* q    = (const float*)d_in[0];
    const float* k    = (const float*)d_in[1];
    const float* l    = (const float*)d_in[2];
    const float* v    = (const float*)d_in[3];
    const float* Wq   = (const float*)d_in[4];
    const float* Wk   = (const float*)d_in[5];
    const float* Wv   = (const float*)d_in[6];
    const float* Wout = (const float*)d_in[7];
    float* out = (float*)d_out;

    float* ws  = (float*)d_ws;
    float* qhp = ws + 0 * PROJ_N;
    float* khp = ws + 1 * PROJ_N;
    float* lhp = ws + 2 * PROJ_N;
    float* vhp = ws + 3 * PROJ_N;
    float* atp = ws + 4 * PROJ_N;

    proj4_kernel<<<dim3(384 / 64, 512 / 64, 4), 256, 0, stream>>>(
        q, k, l, v, Wq, Wk, Wv, ws);
    attn3d_mfma_kernel<<<dim3(16 * NQC), 512, 0, stream>>>(qhp, khp, lhp, vhp, atp);
    outproj_kernel<<<dim3(384 / 64, 512 / 64), 256, 0, stream>>>(atp, Wout, out);
}